// Round 1
// baseline (414.819 us; speedup 1.0000x reference)
//
#include <hip/hip_runtime.h>

#define TT 1024
#define NN 64
#define PF 8
#define SOS 1
#define EOSI 2

__global__ __launch_bounds__(64) void crf_fwd(const float* __restrict__ h,
                                              const float* __restrict__ mask,
                                              const float* __restrict__ trans,
                                              float* __restrict__ out) {
  const int b = blockIdx.x;
  const int lane = threadIdx.x;
  const float* hb = h + (size_t)b * TT * NN;

  __shared__ float pbuf[NN];

  // E row for this lane: er[j] = exp(trans[lane][j])  (NEG entries -> exact 0)
  float er[NN];
#pragma unroll
  for (int c = 0; c < NN / 4; ++c) {
    float4 t4 = *reinterpret_cast<const float4*>(trans + lane * NN + c * 4);
    er[4 * c + 0] = __expf(t4.x);
    er[4 * c + 1] = __expf(t4.y);
    er[4 * c + 2] = __expf(t4.z);
    er[4 * c + 3] = __expf(t4.w);
  }
  const float e2 = __expf(trans[EOSI * NN + lane]);  // exp(trans[EOS][lane])

  // len = sum(mask[b,:])  (mask is a prefix mask by construction)
  float ls = 0.f;
#pragma unroll
  for (int c = 0; c < 4; ++c) {
    float4 m4 = *reinterpret_cast<const float4*>(mask + (size_t)b * TT + c * 256 + lane * 4);
    ls += (m4.x + m4.y) + (m4.z + m4.w);
  }
#pragma unroll
  for (int m = 1; m < 64; m <<= 1) ls += __shfl_xor(ls, m, 64);
  const int len = (int)(ls + 0.5f);

  // init: p = one-hot at SOS (exp domain), running log-offset M = 0
  pbuf[lane] = (lane == SOS) ? 1.0f : 0.0f;
  asm volatile("s_waitcnt lgkmcnt(0)" ::: "memory");

  float M = 0.0f;

  // h prefetch: 8-deep rotating register buffer (static indices only)
  float cur[PF], nxt[PF];
#pragma unroll
  for (int k = 0; k < PF; ++k) cur[k] = hb[k * NN + lane];

  for (int t = 0; t < len; t += PF) {
    // issue next group's loads early (latency cover ~8 steps)
#pragma unroll
    for (int k = 0; k < PF; ++k) {
      int tt = t + PF + k;
      tt = (tt < TT) ? tt : (TT - 1);
      nxt[k] = hb[tt * NN + lane];
    }
#pragma unroll
    for (int k = 0; k < PF; ++k) {
      if (t + k < len) {  // wave-uniform: len identical across the wave
        float a0 = 0.f, a1 = 0.f, a2 = 0.f, a3 = 0.f;
        const float4* p4 = reinterpret_cast<const float4*>(pbuf);
#pragma unroll
        for (int c = 0; c < NN / 4; ++c) {
          float4 pv = p4[c];  // broadcast ds_read_b128, conflict-free
          a0 = fmaf(er[4 * c + 0], pv.x, a0);
          a1 = fmaf(er[4 * c + 1], pv.y, a1);
          a2 = fmaf(er[4 * c + 2], pv.z, a2);
          a3 = fmaf(er[4 * c + 3], pv.w, a3);
        }
        float S = (a0 + a1) + (a2 + a3);
        float pn = __expf(cur[k]) * S;
        if ((k & 3) == 3) {
          // renormalize every 4 steps: p /= max, M += log(max)
          float mm = pn;
#pragma unroll
          for (int m = 1; m < 64; m <<= 1) mm = fmaxf(mm, __shfl_xor(mm, m, 64));
          M += __logf(mm);
          pn *= __builtin_amdgcn_rcpf(mm);
        }
        pbuf[lane] = pn;
        // order LDS write before next step's reads WITHOUT draining vmcnt
        // (h prefetch stays in flight; __syncthreads would emit vmcnt(0))
        asm volatile("s_waitcnt lgkmcnt(0)" ::: "memory");
      }
    }
#pragma unroll
    for (int k = 0; k < PF; ++k) cur[k] = nxt[k];
  }

  // out[b] = M + log( sum_i p_i * exp(trans[EOS,i]) )
  float v = pbuf[lane] * e2;
#pragma unroll
  for (int m = 1; m < 64; m <<= 1) v += __shfl_xor(v, m, 64);
  if (lane == 0) out[b] = M + __logf(v);
}

extern "C" void kernel_launch(void* const* d_in, const int* in_sizes, int n_in,
                              void* d_out, int out_size, void* d_ws, size_t ws_size,
                              hipStream_t stream) {
  const float* h = (const float*)d_in[0];
  const float* mask = (const float*)d_in[1];
  const float* trans = (const float*)d_in[2];
  float* out = (float*)d_out;
  const int B = in_sizes[1] / TT;  // 256
  hipLaunchKernelGGL(crf_fwd, dim3(B), dim3(64), 0, stream, h, mask, trans, out);
}

// Round 2
// 374.467 us; speedup vs baseline: 1.1078x; 1.1078x over previous
//
#include <hip/hip_runtime.h>

#define TT 1024
#define NN 64
#define PF 8
#define SOS 1
#define EOSI 2
#define REFL 8  // reference lane for renormalization (a non-special tag)

typedef float f32x2 __attribute__((ext_vector_type(2)));
typedef float f32x4 __attribute__((ext_vector_type(4)));

__global__ __launch_bounds__(64) void crf_fwd(const float* __restrict__ h,
                                              const float* __restrict__ mask,
                                              const float* __restrict__ trans,
                                              float* __restrict__ out) {
  const int b = blockIdx.x;
  const int lane = threadIdx.x;
  const float* hb = h + (size_t)b * TT * NN;

  __shared__ float pbuf[NN];

  // E row for this lane as float2 pairs: er2[c] = {exp(trans[lane][2c]), exp(trans[lane][2c+1])}
  f32x2 er2[NN / 2];
#pragma unroll
  for (int c = 0; c < NN / 4; ++c) {
    float4 t4 = *reinterpret_cast<const float4*>(trans + lane * NN + c * 4);
    er2[2 * c + 0] = f32x2{__expf(t4.x), __expf(t4.y)};
    er2[2 * c + 1] = f32x2{__expf(t4.z), __expf(t4.w)};
  }
  const float e2 = __expf(trans[EOSI * NN + lane]);

  // len = sum(mask[b,:])  (prefix mask)
  float ls = 0.f;
#pragma unroll
  for (int c = 0; c < 4; ++c) {
    float4 m4 = *reinterpret_cast<const float4*>(mask + (size_t)b * TT + c * 256 + lane * 4);
    ls += (m4.x + m4.y) + (m4.z + m4.w);
  }
#pragma unroll
  for (int m = 1; m < 64; m <<= 1) ls += __shfl_xor(ls, m, 64);
  const int len = (int)(ls + 0.5f);

  pbuf[lane] = (lane == SOS) ? 1.0f : 0.0f;
  asm volatile("s_waitcnt lgkmcnt(0)" ::: "memory");

  float M = 0.0f;

  float cur[PF], nxt[PF];
#pragma unroll
  for (int k = 0; k < PF; ++k) cur[k] = hb[k * NN + lane];

  const int nfull = len >> 3;
  const int tail = len & 7;

  // One step of the recurrence (macro-ish lambda; all indices compile-time via unroll)
  auto step = [&](float eh, bool renorm) {
    f32x2 ac[8];
#pragma unroll
    for (int i = 0; i < 8; ++i) ac[i] = f32x2{0.f, 0.f};
    const f32x4* p4 = reinterpret_cast<const f32x4*>(pbuf);
#pragma unroll
    for (int c = 0; c < NN / 4; ++c) {
      f32x4 pv = p4[c];  // broadcast ds_read_b128, conflict-free
      f32x2 plo = {pv.x, pv.y};
      f32x2 phi = {pv.z, pv.w};
      asm("v_pk_fma_f32 %0, %1, %2, %0" : "+v"(ac[(2 * c) & 7]) : "v"(er2[2 * c]), "v"(plo));
      asm("v_pk_fma_f32 %0, %1, %2, %0" : "+v"(ac[(2 * c + 1) & 7]) : "v"(er2[2 * c + 1]), "v"(phi));
    }
    // pairwise tree sum of 8 packed accumulators
    ac[0] += ac[1]; ac[2] += ac[3]; ac[4] += ac[5]; ac[6] += ac[7];
    ac[0] += ac[2]; ac[4] += ac[6];
    ac[0] += ac[4];
    float S = ac[0].x + ac[0].y;
    float pn = eh * S;
    if (renorm) {
      // single-lane broadcast renorm: ~15 cyc vs ~720 cyc butterfly max
      float s8 = __int_as_float(__builtin_amdgcn_readlane(__float_as_int(pn), REFL));
      pn *= __builtin_amdgcn_rcpf(s8);
      M += __logf(s8);  // off the p-chain
    }
    pbuf[lane] = pn;
    asm volatile("s_waitcnt lgkmcnt(0)" ::: "memory");
  };

  for (int g = 0; g < nfull; ++g) {
    // prefetch next group's h (off-chain; ~900 cyc HBM latency covered by 8 steps)
    const int t0 = (g + 1) * PF;
#pragma unroll
    for (int k = 0; k < PF; ++k) {
      int tt = t0 + k;
      tt = (tt < TT) ? tt : (TT - 1);
      nxt[k] = hb[tt * NN + lane];
    }
    // hoist exp(h) off the chain
    float eh[PF];
#pragma unroll
    for (int k = 0; k < PF; ++k) eh[k] = __expf(cur[k]);
#pragma unroll
    for (int k = 0; k < PF; ++k) step(eh[k], (k & 1) == 1);
#pragma unroll
    for (int k = 0; k < PF; ++k) cur[k] = nxt[k];
  }
  // tail (< 8 steps)
#pragma unroll
  for (int k = 0; k < PF; ++k) {
    if (k < tail) step(__expf(cur[k]), (k & 1) == 1);
  }

  // out[b] = M + log( sum_i p_i * exp(trans[EOS,i]) )  (one-time butterfly is fine here)
  float v = pbuf[lane] * e2;
#pragma unroll
  for (int m = 1; m < 64; m <<= 1) v += __shfl_xor(v, m, 64);
  if (lane == 0) out[b] = M + __logf(v);
}

extern "C" void kernel_launch(void* const* d_in, const int* in_sizes, int n_in,
                              void* d_out, int out_size, void* d_ws, size_t ws_size,
                              hipStream_t stream) {
  const float* h = (const float*)d_in[0];
  const float* mask = (const float*)d_in[1];
  const float* trans = (const float*)d_in[2];
  float* out = (float*)d_out;
  const int B = in_sizes[1] / TT;  // 256
  hipLaunchKernelGGL(crf_fwd, dim3(B), dim3(64), 0, stream, h, mask, trans, out);
}

// Round 3
// 307.725 us; speedup vs baseline: 1.3480x; 1.2169x over previous
//
#include <hip/hip_runtime.h>

#define BATCH 256
#define TT 1024
#define NN 64
#define CHUNK 64
#define NCH (TT / CHUNK)  // 16
#define SOS 1
#define EOSI 2
#define LN2F 0.69314718055994531f

typedef short bf16x8 __attribute__((ext_vector_type(8)));
typedef float f32x4 __attribute__((ext_vector_type(4)));

__device__ __forceinline__ unsigned short f2bf(float x) {
  unsigned u = __float_as_uint(x);
  u += 0x7fffu + ((u >> 16) & 1u);
  return (unsigned short)(u >> 16);
}
__device__ __forceinline__ float bf2f(unsigned short v) {
  return __uint_as_float(((unsigned)v) << 16);
}
// column-major (X^T row-major) storage of a 64x64 bf16 matrix, 8KB.
// element (row r, col c) at byte: c*128 + (2r ^ ((c&7)<<4))  [swizzle vs 128B-stride conflicts]
__device__ __forceinline__ int colm(int r, int c) {
  return c * 128 + ((2 * r) ^ ((c & 7) << 4));
}

__device__ __forceinline__ int wave_len(const float* mask, int b, int l) {
  float ls = 0.f;
#pragma unroll
  for (int i = 0; i < 16; ++i) ls += mask[b * TT + i * 64 + l];
#pragma unroll
  for (int m = 1; m < 64; m <<= 1) ls += __shfl_xor(ls, m, 64);
  return (int)(ls + 0.5f);
}

// ---------------- Kernel A: per (batch, chunk) wave computes chunk matrix ----------------
__global__ __launch_bounds__(64) void crf_chunk(const float* __restrict__ h,
                                                const float* __restrict__ mask,
                                                const float* __restrict__ trans,
                                                unsigned short* __restrict__ mats,
                                                float* __restrict__ scales) {
  __shared__ char lds[17408];  // R ping-pong 2x8192 + ehs 256
  const int l = threadIdx.x;
  char* R0 = lds;
  char* R1 = lds + 8192;
  float* ehs = (float*)(lds + 16384);

  const int gw = blockIdx.x;
  const int b = gw >> 4, c = gw & (NCH - 1);

  const int len = wave_len(mask, b, l);
  const int t0 = c * CHUNK;
  if (t0 >= len) return;  // chunk fully masked; kernel B never reads it
  const int tend = min(t0 + CHUNK, len);

  // E fragments (A operand), resident in regs: E[row][k], row=16I+(l&15), k=32Kc+8*(l>>4)+e
  bf16x8 ef[4][2];
#pragma unroll
  for (int I = 0; I < 4; ++I)
#pragma unroll
    for (int Kc = 0; Kc < 2; ++Kc) {
      const int row = 16 * I + (l & 15);
      const int k0 = 32 * Kc + 8 * (l >> 4);
      const float* p = trans + row * 64 + k0;
      bf16x8 v;
#pragma unroll
      for (int e = 0; e < 8; ++e) v[e] = (short)f2bf(__expf(p[e]));
      ef[I][Kc] = v;
    }

  // R = Identity (colM) in R0
#pragma unroll
  for (int i = 0; i < 8; ++i) *(f32x4*)(R0 + (i * 64 + l) * 16) = f32x4{0.f, 0.f, 0.f, 0.f};
  *(unsigned short*)(R0 + colm(l, l)) = 0x3F80;  // bf16 1.0 on diagonal

  char* Rc = R0;
  char* Rn = R1;
  float sumLog = 0.f;

  float hv = h[((size_t)b * TT + t0) * NN + l];  // software prefetch, 1 step deep
  for (int t = t0; t < tend; ++t) {
    const int tn = (t + 1 < tend) ? t + 1 : t;
    float hv_next = h[((size_t)b * TT + tn) * NN + l];
    ehs[l] = __expf(hv);

    f32x4 acc[4][4];
#pragma unroll
    for (int I = 0; I < 4; ++I)
#pragma unroll
      for (int J = 0; J < 4; ++J) acc[I][J] = f32x4{0.f, 0.f, 0.f, 0.f};

    // C = E * R   (A=E regs, B=R colM)
#pragma unroll
    for (int J = 0; J < 4; ++J) {
      const int cc = 16 * J + (l & 15);
#pragma unroll
      for (int Kc = 0; Kc < 2; ++Kc) {
        const int k0 = 32 * Kc + 8 * (l >> 4);
        bf16x8 bf = *(bf16x8*)(Rc + cc * 128 + ((2 * k0) ^ ((cc & 7) << 4)));
#pragma unroll
        for (int I = 0; I < 4; ++I)
          acc[I][J] = __builtin_amdgcn_mfma_f32_16x16x32_bf16(ef[I][Kc], bf, acc[I][J], 0, 0, 0);
      }
    }

    // row-scale by eh (row = 16I + 4*(l>>4) + reg) and global max
    float mx = 0.f;
#pragma unroll
    for (int I = 0; I < 4; ++I) {
      f32x4 a4 = *(f32x4*)((char*)ehs + (16 * I + 4 * (l >> 4)) * 4);
#pragma unroll
      for (int J = 0; J < 4; ++J) {
        acc[I][J] *= a4;
        mx = fmaxf(mx, fmaxf(fmaxf(acc[I][J][0], acc[I][J][1]), fmaxf(acc[I][J][2], acc[I][J][3])));
      }
    }
#pragma unroll
    for (int m = 1; m < 64; m <<= 1) mx = fmaxf(mx, __shfl_xor(mx, m, 64));
    const int k = (__float_as_int(mx) >> 23) - 127;           // mx > 0 guaranteed
    const float sc = __int_as_float((127 - k) << 23);          // exact 2^-k
    sumLog += (float)k * LN2F;

    // cvt + store new R (colM), rows 16I+4h+{0..3} contiguous -> one b64 per (I,J)
#pragma unroll
    for (int I = 0; I < 4; ++I) {
      const int r0 = 16 * I + 4 * (l >> 4);
#pragma unroll
      for (int J = 0; J < 4; ++J) {
        const int cc = 16 * J + (l & 15);
        unsigned q0 = (unsigned)f2bf(acc[I][J][0] * sc) | ((unsigned)f2bf(acc[I][J][1] * sc) << 16);
        unsigned q1 = (unsigned)f2bf(acc[I][J][2] * sc) | ((unsigned)f2bf(acc[I][J][3] * sc) << 16);
        *(uint2*)(Rn + cc * 128 + ((2 * r0) ^ ((cc & 7) << 4))) = uint2{q0, q1};
      }
    }
    { char* tmp = Rc; Rc = Rn; Rn = tmp; }
    hv = hv_next;
  }

  // write chunk matrix row-major to global: lane l owns row l
  unsigned short* gm = mats + (size_t)(b * NCH + c) * 4096;
#pragma unroll
  for (int j0 = 0; j0 < 64; j0 += 8) {
    unsigned qq[4];
#pragma unroll
    for (int p = 0; p < 4; ++p) {
      unsigned short e0 = *(unsigned short*)(Rc + colm(l, j0 + 2 * p));
      unsigned short e1 = *(unsigned short*)(Rc + colm(l, j0 + 2 * p + 1));
      qq[p] = (unsigned)e0 | ((unsigned)e1 << 16);
    }
    *(uint4*)(gm + l * 64 + j0) = uint4{qq[0], qq[1], qq[2], qq[3]};
  }
  if (l == 0) scales[b * NCH + c] = sumLog;
}

// ---------------- Kernel B: fold chunk matrices per batch, emit logZ ----------------
__global__ __launch_bounds__(64) void crf_fold(const float* __restrict__ mask,
                                               const float* __restrict__ trans,
                                               const unsigned short* __restrict__ mats,
                                               const float* __restrict__ scales,
                                               float* __restrict__ out) {
  __shared__ char lds[16640];
  const int l = threadIdx.x;
  char* R0 = lds;
  char* R1 = lds + 8192;
  const int b = blockIdx.x;

  const int len = wave_len(mask, b, l);
  const int nc = (len + CHUNK - 1) / CHUNK;

  // init R = chunk 0 matrix (global rowM -> LDS colM); lane l owns row l
  const uint4* grow = (const uint4*)(mats + (size_t)b * NCH * 4096 + l * 64);
#pragma unroll
  for (int j0 = 0; j0 < 8; ++j0) {
    uint4 q = grow[j0];
    unsigned w[4] = {q.x, q.y, q.z, q.w};
#pragma unroll
    for (int p = 0; p < 4; ++p) {
      *(unsigned short*)(R0 + colm(l, j0 * 8 + 2 * p)) = (unsigned short)(w[p] & 0xffff);
      *(unsigned short*)(R0 + colm(l, j0 * 8 + 2 * p + 1)) = (unsigned short)(w[p] >> 16);
    }
  }

  float stot = 0.f;
  for (int c = 0; c < nc; ++c) stot += scales[b * NCH + c];

  char* Rc = R0;
  char* Rn = R1;
  for (int c = 1; c < nc; ++c) {
    // A-frags from global chunk matrix (row-major)
    bf16x8 af[4][2];
#pragma unroll
    for (int I = 0; I < 4; ++I)
#pragma unroll
      for (int Kc = 0; Kc < 2; ++Kc) {
        const int row = 16 * I + (l & 15);
        af[I][Kc] = *(const bf16x8*)(mats + (size_t)(b * NCH + c) * 4096 + row * 64 + 32 * Kc + 8 * (l >> 4));
      }
    f32x4 acc[4][4];
#pragma unroll
    for (int I = 0; I < 4; ++I)
#pragma unroll
      for (int J = 0; J < 4; ++J) acc[I][J] = f32x4{0.f, 0.f, 0.f, 0.f};
#pragma unroll
    for (int J = 0; J < 4; ++J) {
      const int cc = 16 * J + (l & 15);
#pragma unroll
      for (int Kc = 0; Kc < 2; ++Kc) {
        const int k0 = 32 * Kc + 8 * (l >> 4);
        bf16x8 bf = *(bf16x8*)(Rc + cc * 128 + ((2 * k0) ^ ((cc & 7) << 4)));
#pragma unroll
        for (int I = 0; I < 4; ++I)
          acc[I][J] = __builtin_amdgcn_mfma_f32_16x16x32_bf16(af[I][Kc], bf, acc[I][J], 0, 0, 0);
      }
    }
    float mx = 0.f;
#pragma unroll
    for (int I = 0; I < 4; ++I)
#pragma unroll
      for (int J = 0; J < 4; ++J)
        mx = fmaxf(mx, fmaxf(fmaxf(acc[I][J][0], acc[I][J][1]), fmaxf(acc[I][J][2], acc[I][J][3])));
#pragma unroll
    for (int m = 1; m < 64; m <<= 1) mx = fmaxf(mx, __shfl_xor(mx, m, 64));
    const int k = (__float_as_int(mx) >> 23) - 127;
    const float sc = __int_as_float((127 - k) << 23);
    stot += (float)k * LN2F;
#pragma unroll
    for (int I = 0; I < 4; ++I) {
      const int r0 = 16 * I + 4 * (l >> 4);
#pragma unroll
      for (int J = 0; J < 4; ++J) {
        const int cc = 16 * J + (l & 15);
        unsigned q0 = (unsigned)f2bf(acc[I][J][0] * sc) | ((unsigned)f2bf(acc[I][J][1] * sc) << 16);
        unsigned q1 = (unsigned)f2bf(acc[I][J][2] * sc) | ((unsigned)f2bf(acc[I][J][3] * sc) << 16);
        *(uint2*)(Rn + cc * 128 + ((2 * r0) ^ ((cc & 7) << 4))) = uint2{q0, q1};
      }
    }
    { char* tmp = Rc; Rc = Rn; Rn = tmp; }
  }

  // logZ = log( sum_i exp(trans[EOS,i]) * R[i, SOS] ) + stot
  float r = bf2f(*(unsigned short*)(Rc + colm(l, SOS)));
  float v = __expf(trans[EOSI * 64 + l]);
  float s = r * v;
#pragma unroll
  for (int m = 1; m < 64; m <<= 1) s += __shfl_xor(s, m, 64);
  if (l == 0) out[b] = __logf(s) + stot;
}

extern "C" void kernel_launch(void* const* d_in, const int* in_sizes, int n_in,
                              void* d_out, int out_size, void* d_ws, size_t ws_size,
                              hipStream_t stream) {
  const float* h = (const float*)d_in[0];
  const float* mask = (const float*)d_in[1];
  const float* trans = (const float*)d_in[2];
  float* out = (float*)d_out;

  unsigned short* mats = (unsigned short*)d_ws;                       // 256*16*4096*2B = 32 MB
  float* scales = (float*)((char*)d_ws + (size_t)BATCH * NCH * 4096 * 2);  // +16 KB

  hipLaunchKernelGGL(crf_chunk, dim3(BATCH * NCH), dim3(64), 0, stream, h, mask, trans, mats, scales);
  hipLaunchKernelGGL(crf_fold, dim3(BATCH), dim3(64), 0, stream, mask, trans, mats, scales, out);
}

// Round 4
// 179.175 us; speedup vs baseline: 2.3152x; 1.7175x over previous
//
#include <hip/hip_runtime.h>

#define BATCH 256
#define TT 1024
#define NN 64
#define CHUNK 64
#define NCH (TT / CHUNK)  // 16
#define SOS 1
#define EOSI 2
#define LN2F 0.6931471805599453f
#define LOG2E 1.4426950408889634f

typedef short bf16x8 __attribute__((ext_vector_type(8)));
typedef float f32x4 __attribute__((ext_vector_type(4)));

__device__ __forceinline__ unsigned short f2bf(float x) {
  unsigned u = __float_as_uint(x);
  u += 0x7fffu + ((u >> 16) & 1u);
  return (unsigned short)(u >> 16);
}
__device__ __forceinline__ float bf2f(unsigned short v) { return __uint_as_float(((unsigned)v) << 16); }

__device__ __forceinline__ unsigned cvtpk(float lo, float hi) {
  unsigned r;
  asm("v_cvt_pk_bf16_f32 %0, %1, %2" : "=v"(r) : "v"(lo), "v"(hi));
  return r;
}

// Tiled contraction-major LDS layout for a 64x64 bf16 matrix (8 KB):
// element (k, c) at byte ((c>>4)<<11) + ((k>>5)<<10) + (((k>>3)&3)<<8) + ((c&15)<<4) + ((k&7)<<1).
// B-frag read (J,Kc): addr = 1024*(2J+Kc) + 16*lane  -> lane-linear, conflict-free.
// Acc write (I,J): 64 lanes cover 512 contiguous bytes  -> conflict-free.
__device__ __forceinline__ int tadr(int k, int c) {
  return ((c >> 4) << 11) + ((k >> 5) << 10) + (((k >> 3) & 3) << 8) + ((c & 15) << 4) + ((k & 7) << 1);
}

__device__ __forceinline__ int wave_len(const float* mask, int b, int l) {
  float ls = 0.f;
#pragma unroll
  for (int c = 0; c < 4; ++c) {
    float4 m4 = *reinterpret_cast<const float4*>(mask + (size_t)b * TT + c * 256 + l * 4);
    ls += (m4.x + m4.y) + (m4.z + m4.w);
  }
#pragma unroll
  for (int m = 1; m < 64; m <<= 1) ls += __shfl_xor(ls, m, 64);
  return (int)(ls + 0.5f);
}

// ---------------- Kernel A: per (batch, chunk) wave builds the chunk transition matrix ----------------
__global__ __launch_bounds__(64, 4) void crf_chunk(const float* __restrict__ h,
                                                   const float* __restrict__ mask,
                                                   const float* __restrict__ trans,
                                                   unsigned short* __restrict__ mats,
                                                   float* __restrict__ scales) {
  __shared__ char R[8192 + 256];  // tiled R + ehs[64]
  float* ehs = (float*)(R + 8192);
  const int l = threadIdx.x;
  const int b = blockIdx.x & (BATCH - 1);  // chunk-major grid: CU gets one batch's chunks
  const int c = blockIdx.x >> 8;

  const int len = wave_len(mask, b, l);
  const int t0 = c * CHUNK;
  if (t0 >= len) return;
  const int nstep = min(CHUNK, len - t0);

  // E fragments (A operand), resident in regs (layout validated in R3)
  bf16x8 ef[4][2];
#pragma unroll
  for (int I = 0; I < 4; ++I)
#pragma unroll
    for (int Kc = 0; Kc < 2; ++Kc) {
      const int row = 16 * I + (l & 15);
      const int k0 = 32 * Kc + 8 * (l >> 4);
      const float* p = trans + row * 64 + k0;
      bf16x8 v;
#pragma unroll
      for (int e = 0; e < 8; ++e) v[e] = (short)f2bf(__expf(p[e]));
      ef[I][Kc] = v;
    }

  // R = identity (tiled)
#pragma unroll
  for (int i = 0; i < 8; ++i) *(f32x4*)(R + ((i * 64 + l) << 4)) = f32x4{0.f, 0.f, 0.f, 0.f};
  *(unsigned short*)(R + tadr(l, l)) = 0x3F80;  // bf16 1.0
  asm volatile("s_waitcnt lgkmcnt(0)" ::: "memory");

  int eA = 0, eB = 0, esum = 0;  // stale-by-2 renorm exponents (exact bookkeeping)
  float hv = h[((size_t)b * TT + t0) * NN + l];

  for (int t = 0; t < nstep; ++t) {
    const int tn = (t + 1 < nstep) ? t + 1 : t;
    float hv_next = h[((size_t)b * TT + t0 + tn) * NN + l];  // off-chain prefetch
    ehs[l] = exp2f(fmaf(hv, LOG2E, (float)(-eA)));           // exp(h) * 2^-eA fused
    esum += eA;

    float mloc = 0.f;
#pragma unroll
    for (int J = 0; J < 4; ++J) {
      // lane-linear conflict-free B-frag reads of col-block J
      bf16x8 f0 = *(bf16x8*)(R + ((2 * J) << 10) + (l << 4));
      bf16x8 f1 = *(bf16x8*)(R + ((2 * J + 1) << 10) + (l << 4));
      f32x4 a[4];
#pragma unroll
      for (int I = 0; I < 4; ++I) a[I] = f32x4{0.f, 0.f, 0.f, 0.f};
#pragma unroll
      for (int I = 0; I < 4; ++I) {
        a[I] = __builtin_amdgcn_mfma_f32_16x16x32_bf16(ef[I][0], f0, a[I], 0, 0, 0);
        a[I] = __builtin_amdgcn_mfma_f32_16x16x32_bf16(ef[I][1], f1, a[I], 0, 0, 0);
      }
      // per-J epilogue: row-scale by eh, track max, cvt, in-place write of col-block J
#pragma unroll
      for (int I = 0; I < 4; ++I) {
        f32x4 s4 = *(f32x4*)(ehs + 16 * I + 4 * (l >> 4));  // broadcast
        f32x4 v = a[I] * s4;
        mloc = fmaxf(mloc, fmaxf(fmaxf(v[0], v[1]), fmaxf(v[2], v[3])));
        const int r0 = 16 * I + 4 * (l >> 4);
        const int cc = 16 * J + (l & 15);
        *(uint2*)(R + tadr(r0, cc)) = uint2{cvtpk(v[0], v[1]), cvtpk(v[2], v[3])};
      }
    }
    // off-chain wave max -> exponent for step t+2
#pragma unroll
    for (int m = 1; m < 64; m <<= 1) mloc = fmaxf(mloc, __shfl_xor(mloc, m, 64));
    const int eNew = (__float_as_int(mloc) >> 23) - 127;
    eA = eB;
    eB = eNew;
    hv = hv_next;
    asm volatile("s_waitcnt lgkmcnt(0)" ::: "memory");
  }

  // final exact renorm (max -> [1,2)) and row-major global store
  const float scF = __int_as_float((127 - eB) << 23);  // 2^-eB, exact
  esum += eB;
  unsigned short* gm = mats + (size_t)(b * NCH + c) * 4096;
#pragma unroll
  for (int j0 = 0; j0 < 64; j0 += 8) {
    unsigned q[4];
#pragma unroll
    for (int p = 0; p < 4; ++p) {
      float x0 = bf2f(*(unsigned short*)(R + tadr(l, j0 + 2 * p))) * scF;
      float x1 = bf2f(*(unsigned short*)(R + tadr(l, j0 + 2 * p + 1))) * scF;
      q[p] = cvtpk(x0, x1);  // pow2 scaling is exact; repack lossless
    }
    *(uint4*)(gm + l * 64 + j0) = uint4{q[0], q[1], q[2], q[3]};
  }
  if (l == 0) scales[b * NCH + c] = LN2F * (float)esum;
}

// ---------------- Kernel B: per-batch VECTOR fold p <- M_c p (in-lane dots, no cross-lane) ----------------
__global__ __launch_bounds__(64) void crf_fold(const float* __restrict__ mask,
                                               const float* __restrict__ trans,
                                               const unsigned short* __restrict__ mats,
                                               const float* __restrict__ scales,
                                               float* __restrict__ out) {
  __shared__ float pv[NN];
  const int l = threadIdx.x;
  const int b = blockIdx.x;
  const int len = wave_len(mask, b, l);
  const int nc = (len + CHUNK - 1) / CHUNK;

  float stot = (l < nc) ? scales[b * NCH + l] : 0.f;
#pragma unroll
  for (int m = 1; m < 64; m <<= 1) stot += __shfl_xor(stot, m, 64);

  pv[l] = (l == SOS) ? 1.f : 0.f;
  asm volatile("s_waitcnt lgkmcnt(0)" ::: "memory");

  int eA = 0, esum = 0;  // stale-by-1 renorm
  for (int c = 0; c < nc; ++c) {
    const uint4* Mr = (const uint4*)(mats + (size_t)(b * NCH + c) * 4096 + l * 64);
    uint4 U[8];
#pragma unroll
    for (int j = 0; j < 8; ++j) U[j] = Mr[j];  // whole row l, issued up-front (p-independent)
    const float sc = __int_as_float((127 - eA) << 23);
    esum += eA;
    float ac0 = 0.f, ac1 = 0.f, ac2 = 0.f, ac3 = 0.f;
#pragma unroll
    for (int j = 0; j < 8; ++j) {
      f32x4 pa = *(f32x4*)(pv + j * 8);      // broadcast reads
      f32x4 pb = *(f32x4*)(pv + j * 8 + 4);
      uint4 q = U[j];
      ac0 = fmaf(__uint_as_float(q.x << 16), pa[0], ac0);
      ac1 = fmaf(__uint_as_float(q.x & 0xffff0000u), pa[1], ac1);
      ac2 = fmaf(__uint_as_float(q.y << 16), pa[2], ac2);
      ac3 = fmaf(__uint_as_float(q.y & 0xffff0000u), pa[3], ac3);
      ac0 = fmaf(__uint_as_float(q.z << 16), pb[0], ac0);
      ac1 = fmaf(__uint_as_float(q.z & 0xffff0000u), pb[1], ac1);
      ac2 = fmaf(__uint_as_float(q.w << 16), pb[2], ac2);
      ac3 = fmaf(__uint_as_float(q.w & 0xffff0000u), pb[3], ac3);
    }
    float pn = ((ac0 + ac1) + (ac2 + ac3)) * sc;
    float mm = pn;
#pragma unroll
    for (int m = 1; m < 64; m <<= 1) mm = fmaxf(mm, __shfl_xor(mm, m, 64));
    eA = (__float_as_int(mm) >> 23) - 127;  // for NEXT fold (off-chain slack)
    pv[l] = pn;
    asm volatile("s_waitcnt lgkmcnt(0)" ::: "memory");
  }

  float s = pv[l] * __expf(trans[EOSI * NN + l]);
#pragma unroll
  for (int m = 1; m < 64; m <<= 1) s += __shfl_xor(s, m, 64);
  if (l == 0) out[b] = __logf(s) + LN2F * (float)esum + stot;
}

extern "C" void kernel_launch(void* const* d_in, const int* in_sizes, int n_in,
                              void* d_out, int out_size, void* d_ws, size_t ws_size,
                              hipStream_t stream) {
  const float* h = (const float*)d_in[0];
  const float* mask = (const float*)d_in[1];
  const float* trans = (const float*)d_in[2];
  float* out = (float*)d_out;

  unsigned short* mats = (unsigned short*)d_ws;  // 256*16*4096*2B = 32 MB
  float* scales = (float*)((char*)d_ws + (size_t)BATCH * NCH * 4096 * 2);

  hipLaunchKernelGGL(crf_chunk, dim3(BATCH * NCH), dim3(64), 0, stream, h, mask, trans, mats, scales);
  hipLaunchKernelGGL(crf_fold, dim3(BATCH), dim3(64), 0, stream, mask, trans, mats, scales, out);
}

// Round 5
// 145.960 us; speedup vs baseline: 2.8420x; 1.2276x over previous
//
#include <hip/hip_runtime.h>

#define BATCH 256
#define TT 1024
#define NN 64
#define CHUNK 64
#define NCH (TT / CHUNK)  // 16
#define SOS 1
#define EOSI 2
#define LN2F 0.6931471805599453f
#define LOG2E 1.4426950408889634f

typedef short bf16x8 __attribute__((ext_vector_type(8)));
typedef float f32x4 __attribute__((ext_vector_type(4)));
typedef float f32x2 __attribute__((ext_vector_type(2)));

__device__ __forceinline__ unsigned short f2bf(float x) {
  unsigned u = __float_as_uint(x);
  u += 0x7fffu + ((u >> 16) & 1u);
  return (unsigned short)(u >> 16);
}
__device__ __forceinline__ float bf2f(unsigned short v) { return __uint_as_float(((unsigned)v) << 16); }

__device__ __forceinline__ unsigned cvtpk(float lo, float hi) {
  unsigned r;
  asm("v_cvt_pk_bf16_f32 %0, %1, %2" : "=v"(r) : "v"(lo), "v"(hi));
  return r;
}
__device__ __forceinline__ f32x2 pkmul(f32x2 a, f32x2 b) {
  f32x2 r;
  asm("v_pk_mul_f32 %0, %1, %2" : "=v"(r) : "v"(a), "v"(b));
  return r;
}

// Tiled contraction-major LDS layout for 64x64 bf16 (8 KB), validated R4:
// (k,c) at byte ((c>>4)<<11) + ((k>>5)<<10) + (((k>>3)&3)<<8) + ((c&15)<<4) + ((k&7)<<1)
// B-frag (J,Kc): addr = 1024*(2J+Kc) + 16*lane (lane-linear, conflict-free)
__device__ __forceinline__ int tadr(int k, int c) {
  return ((c >> 4) << 11) + ((k >> 5) << 10) + (((k >> 3) & 3) << 8) + ((c & 15) << 4) + ((k & 7) << 1);
}

__device__ __forceinline__ int wave_len(const float* mask, int b, int l) {
  float ls = 0.f;
#pragma unroll
  for (int c = 0; c < 4; ++c) {
    float4 m4 = *reinterpret_cast<const float4*>(mask + (size_t)b * TT + c * 256 + l * 4);
    ls += (m4.x + m4.y) + (m4.z + m4.w);
  }
#pragma unroll
  for (int m = 1; m < 64; m <<= 1) ls += __shfl_xor(ls, m, 64);
  return (int)(ls + 0.5f);
}

// ---------------- Kernel A ----------------
__global__ __launch_bounds__(64, 3) void crf_chunk(const float* __restrict__ h,
                                                   const float* __restrict__ mask,
                                                   const float* __restrict__ trans,
                                                   unsigned short* __restrict__ mats,
                                                   float* __restrict__ scales) {
  __shared__ char R[8192 + 256];
  float* ehs = (float*)(R + 8192);
  const int l = threadIdx.x;
  const int h4 = l >> 4;
  const int b = blockIdx.x >> 4;        // row-major: batch spread across CUs
  const int c = blockIdx.x & (NCH - 1);

  const int len = wave_len(mask, b, l);
  const int t0 = c * CHUNK;
  if (t0 >= len) return;
  const int nstep = min(CHUNK, len - t0);

  // E fragments (A operand), resident in regs (layout validated R3/R4)
  bf16x8 ef[4][2];
#pragma unroll
  for (int I = 0; I < 4; ++I)
#pragma unroll
    for (int Kc = 0; Kc < 2; ++Kc) {
      const int row = 16 * I + (l & 15);
      const float* p = trans + row * 64 + 32 * Kc + 8 * h4;
      bf16x8 v;
#pragma unroll
      for (int e = 0; e < 8; ++e) v[e] = (short)f2bf(__expf(p[e]));
      ef[I][Kc] = v;
    }

  // R = identity (tiled)
#pragma unroll
  for (int i = 0; i < 8; ++i) *(f32x4*)(R + ((i * 64 + l) << 4)) = f32x4{0.f, 0.f, 0.f, 0.f};
  *(unsigned short*)(R + tadr(l, l)) = 0x3F80;
  asm volatile("s_waitcnt lgkmcnt(0)" ::: "memory");

  int ePend = 0;  // exponent measured 2 (even) steps ago; applied on even steps
  int esum = 0;
  const float* hp = h + ((size_t)b * TT + t0) * NN + l;
  float hv = *hp;
  hp += NN;

  for (int t = 0; t < nstep; ++t) {
    float hv_next = hv;
    if (t + 1 < nstep) hv_next = *hp;  // off-chain prefetch (wave-uniform cond)
    hp += NN;

    const int ec = ((t & 1) == 0) ? ePend : 0;
    esum += ec;
    ehs[l] = exp2f(fmaf(hv, LOG2E, (float)(-ec)));
    // same-wave LDS pipe order guarantees write-then-read (validated R3/R4)
    f32x4 eh4[4];
#pragma unroll
    for (int I = 0; I < 4; ++I) eh4[I] = *(f32x4*)(ehs + 16 * I + 4 * h4);

    bf16x8 fc0 = *(bf16x8*)(R + 0 + (l << 4));
    bf16x8 fc1 = *(bf16x8*)(R + 1024 + (l << 4));
    float prox = 0.f;
#pragma unroll
    for (int J = 0; J < 4; ++J) {
      bf16x8 fn0, fn1;
      if (J < 3) {  // double-buffer next col-block's B-frags (read-before-write, pipe-ordered)
        fn0 = *(bf16x8*)(R + (2 * J + 2) * 1024 + (l << 4));
        fn1 = *(bf16x8*)(R + (2 * J + 3) * 1024 + (l << 4));
      }
      f32x4 a[4];
#pragma unroll
      for (int I = 0; I < 4; ++I) a[I] = f32x4{0.f, 0.f, 0.f, 0.f};
#pragma unroll
      for (int I = 0; I < 4; ++I) {
        a[I] = __builtin_amdgcn_mfma_f32_16x16x32_bf16(ef[I][0], fc0, a[I], 0, 0, 0);
        a[I] = __builtin_amdgcn_mfma_f32_16x16x32_bf16(ef[I][1], fc1, a[I], 0, 0, 0);
      }
#pragma unroll
      for (int I = 0; I < 4; ++I) {
        f32x2 vlo = pkmul(f32x2{a[I][0], a[I][1]}, f32x2{eh4[I][0], eh4[I][1]});
        f32x2 vhi = pkmul(f32x2{a[I][2], a[I][3]}, f32x2{eh4[I][2], eh4[I][3]});
        if (J == 0 && (I == 1 || I == 2))
          prox = fmaxf(prox, fmaxf(fmaxf(vlo[0], vlo[1]), fmaxf(vhi[0], vhi[1])));
        const int r0 = 16 * I + 4 * h4;
        const int cc = 16 * J + (l & 15);
        *(uint2*)(R + tadr(r0, cc)) = uint2{cvtpk(vlo[0], vlo[1]), cvtpk(vhi[0], vhi[1])};
      }
      fc0 = fn0;
      fc1 = fn1;
    }
    if ((t & 1) == 0) {
      // proxy wave-scale: rows 16-19/32-35 x col 5 sample; self-correcting, pow2-exact
      float px = __int_as_float(__builtin_amdgcn_readlane(__float_as_int(prox), 5));
      ePend = (__float_as_int(px) >> 23) - 127;
    }
    hv = hv_next;
    asm volatile("s_waitcnt lgkmcnt(0)" ::: "memory");
  }

  const float scF = __int_as_float((127 - ePend) << 23);  // 2^-e, exact
  esum += ePend;
  unsigned short* gm = mats + (size_t)(b * NCH + c) * 4096;
#pragma unroll
  for (int j0 = 0; j0 < 64; j0 += 8) {
    unsigned q[4];
#pragma unroll
    for (int p = 0; p < 4; ++p) {
      float x0 = bf2f(*(unsigned short*)(R + tadr(l, j0 + 2 * p))) * scF;
      float x1 = bf2f(*(unsigned short*)(R + tadr(l, j0 + 2 * p + 1))) * scF;
      q[p] = cvtpk(x0, x1);
    }
    *(uint4*)(gm + l * 64 + j0) = uint4{q[0], q[1], q[2], q[3]};
  }
  if (l == 0) scales[b * NCH + c] = LN2F * (float)esum;
}

// ---------------- Kernel B: per-batch vector fold (validated R4) ----------------
__global__ __launch_bounds__(64) void crf_fold(const float* __restrict__ mask,
                                               const float* __restrict__ trans,
                                               const unsigned short* __restrict__ mats,
                                               const float* __restrict__ scales,
                                               float* __restrict__ out) {
  __shared__ float pv[NN];
  const int l = threadIdx.x;
  const int b = blockIdx.x;
  const int len = wave_len(mask, b, l);
  const int nc = (len + CHUNK - 1) / CHUNK;

  float stot = (l < nc) ? scales[b * NCH + l] : 0.f;
#pragma unroll
  for (int m = 1; m < 64; m <<= 1) stot += __shfl_xor(stot, m, 64);

  pv[l] = (l == SOS) ? 1.f : 0.f;
  asm volatile("s_waitcnt lgkmcnt(0)" ::: "memory");

  int eA = 0, esum = 0;
  for (int c = 0; c < nc; ++c) {
    const uint4* Mr = (const uint4*)(mats + (size_t)(b * NCH + c) * 4096 + l * 64);
    uint4 U[8];
#pragma unroll
    for (int j = 0; j < 8; ++j) U[j] = Mr[j];
    const float sc = __int_as_float((127 - eA) << 23);
    esum += eA;
    float ac0 = 0.f, ac1 = 0.f, ac2 = 0.f, ac3 = 0.f;
#pragma unroll
    for (int j = 0; j < 8; ++j) {
      f32x4 pa = *(f32x4*)(pv + j * 8);
      f32x4 pb = *(f32x4*)(pv + j * 8 + 4);
      uint4 q = U[j];
      ac0 = fmaf(__uint_as_float(q.x << 16), pa[0], ac0);
      ac1 = fmaf(__uint_as_float(q.x & 0xffff0000u), pa[1], ac1);
      ac2 = fmaf(__uint_as_float(q.y << 16), pa[2], ac2);
      ac3 = fmaf(__uint_as_float(q.y & 0xffff0000u), pa[3], ac3);
      ac0 = fmaf(__uint_as_float(q.z << 16), pb[0], ac0);
      ac1 = fmaf(__uint_as_float(q.z & 0xffff0000u), pb[1], ac1);
      ac2 = fmaf(__uint_as_float(q.w << 16), pb[2], ac2);
      ac3 = fmaf(__uint_as_float(q.w & 0xffff0000u), pb[3], ac3);
    }
    float pn = ((ac0 + ac1) + (ac2 + ac3)) * sc;
    float mm = pn;
#pragma unroll
    for (int m = 1; m < 64; m <<= 1) mm = fmaxf(mm, __shfl_xor(mm, m, 64));
    eA = (__float_as_int(mm) >> 23) - 127;
    pv[l] = pn;
    asm volatile("s_waitcnt lgkmcnt(0)" ::: "memory");
  }

  float s = pv[l] * __expf(trans[EOSI * NN + l]);
#pragma unroll
  for (int m = 1; m < 64; m <<= 1) s += __shfl_xor(s, m, 64);
  if (l == 0) out[b] = __logf(s) + LN2F * (float)esum + stot;
}

extern "C" void kernel_launch(void* const* d_in, const int* in_sizes, int n_in,
                              void* d_out, int out_size, void* d_ws, size_t ws_size,
                              hipStream_t stream) {
  const float* h = (const float*)d_in[0];
  const float* mask = (const float*)d_in[1];
  const float* trans = (const float*)d_in[2];
  float* out = (float*)d_out;

  unsigned short* mats = (unsigned short*)d_ws;  // 32 MB
  float* scales = (float*)((char*)d_ws + (size_t)BATCH * NCH * 4096 * 2);

  hipLaunchKernelGGL(crf_chunk, dim3(BATCH * NCH), dim3(64), 0, stream, h, mask, trans, mats, scales);
  hipLaunchKernelGGL(crf_fold, dim3(BATCH), dim3(64), 0, stream, mask, trans, mats, scales, out);
}